// Round 5
// baseline (169.873 us; speedup 1.0000x reference)
//
#include <hip/hip_runtime.h>

#define ND 256       // embedding dim
#define NK 512       // centroids
#define LM2 0.0625f  // lambda^2
#define DELTA 0.25f  // approx top-2 gap below this -> exact fp32 rescore

typedef _Float16 f16x8 __attribute__((ext_vector_type(8)));
typedef float f32x4 __attribute__((ext_vector_type(4)));
typedef unsigned short u16x8 __attribute__((ext_vector_type(8)));
typedef unsigned short u16x4 __attribute__((ext_vector_type(4)));

// ---------------- prep: csq[k] and fp16 centroids in MFMA-B-fragment order ----
// Cf layout: [colblk 8][(ks*4+l4) 32][col 64][8 halves]; granule = 16B = one
// lane's B-frag slice. Main kernel stages a colblk panel (32 KB) linearly and
// reads frags with one address register + immediate offsets.
__global__ __launch_bounds__(64) void prep_kernel(const float* __restrict__ Cg,
                                                  float* __restrict__ csq,
                                                  unsigned short* __restrict__ Cf) {
    const int k = blockIdx.x, lane = threadIdx.x;
    float4 v = *(const float4*)(Cg + (size_t)k * ND + lane * 4);
    float s = v.x * v.x + v.y * v.y + v.z * v.z + v.w * v.w;
#pragma unroll
    for (int m = 1; m <= 32; m <<= 1) s += __shfl_xor(s, m, 64);
    if (lane == 0) csq[k] = s;
    u16x4 h;
    h[0] = __builtin_bit_cast(unsigned short, (_Float16)v.x);
    h[1] = __builtin_bit_cast(unsigned short, (_Float16)v.y);
    h[2] = __builtin_bit_cast(unsigned short, (_Float16)v.z);
    h[3] = __builtin_bit_cast(unsigned short, (_Float16)v.w);
    const int colblk = k >> 6, col = k & 63;
    const size_t idx = ((size_t)colblk << 14) + ((((size_t)(lane >> 1) << 6) + col) << 3) + ((lane & 1) << 2);
    *(u16x4*)(Cf + idx) = h;
}

// ---------------- main: TLP-max fused GEMM + top-2 ----------------
// grid 8192 = 1024 rowtiles(128 rows) x 8 colblks(64 cols), XCD-chunked.
// block: 4 waves x 32-row tiles; wave tile 32x64 (acc = 32 AGPR) -> 4 waves/SIMD.
__global__ __launch_bounds__(256, 4) void kmeans_mfma(
    const float* __restrict__ E, const unsigned short* __restrict__ Cf,
    const float* __restrict__ csq, float* __restrict__ partials,
    float* __restrict__ e2s) {
    __shared__ unsigned short Blds[16384];  // 32 KB

    const int tid = threadIdx.x;
    const int l = ((blockIdx.x & 7) << 10) + (blockIdx.x >> 3);  // chunked XCD swizzle
    const int rowtile = l >> 3, colblk = l & 7;
    const int rowbase = rowtile << 7, colbase = colblk << 6;

    const int lane = tid & 63, wid = tid >> 6;
    const int l15 = lane & 15, l4 = lane >> 4;

    // ---- stage B panel (linear 32 KB copy), one barrier ----
    const unsigned short* CfB = Cf + ((size_t)colblk << 14);
#pragma unroll
    for (int i = 0; i < 8; ++i) {
        const int g = tid + i * 256;
        *(u16x8*)&Blds[g << 3] = *(const u16x8*)(CfB + ((size_t)g << 3));
    }
    __syncthreads();

    // ---- barrier-free K-loop ----
    const int wrow = rowbase + wid * 32;
    const float* a0 = E + (size_t)(wrow + l15) * ND + l4 * 8;       // m=0 rows
    const float* a1 = E + (size_t)(wrow + 16 + l15) * ND + l4 * 8;  // m=1 rows

    f32x4 acc[2][4] = {};
    float e2 = 0.f;

    float4 aN[2][2];
    aN[0][0] = *(const float4*)(a0 + 0); aN[0][1] = *(const float4*)(a0 + 4);
    aN[1][0] = *(const float4*)(a1 + 0); aN[1][1] = *(const float4*)(a1 + 4);

#pragma unroll
    for (int ks = 0; ks < 8; ++ks) {
        // B frags (one b128 each; (ks,n) offsets fold into ds immediates)
        u16x8 bf[4];
#pragma unroll
        for (int n = 0; n < 4; ++n)
            bf[n] = *(const u16x8*)&Blds[((((ks << 2) + l4) << 6) + n * 16 + l15) << 3];
        // convert current A chunk to fp16 (+ e2 on colblk 0)
        f16x8 af[2];
#pragma unroll
        for (int m = 0; m < 2; ++m) {
            float4 v0 = aN[m][0], v1 = aN[m][1];
            if (colblk == 0)
                e2 += v0.x * v0.x + v0.y * v0.y + v0.z * v0.z + v0.w * v0.w +
                      v1.x * v1.x + v1.y * v1.y + v1.z * v1.z + v1.w * v1.w;
            u16x8 h;
            h[0] = __builtin_bit_cast(unsigned short, (_Float16)v0.x);
            h[1] = __builtin_bit_cast(unsigned short, (_Float16)v0.y);
            h[2] = __builtin_bit_cast(unsigned short, (_Float16)v0.z);
            h[3] = __builtin_bit_cast(unsigned short, (_Float16)v0.w);
            h[4] = __builtin_bit_cast(unsigned short, (_Float16)v1.x);
            h[5] = __builtin_bit_cast(unsigned short, (_Float16)v1.y);
            h[6] = __builtin_bit_cast(unsigned short, (_Float16)v1.z);
            h[7] = __builtin_bit_cast(unsigned short, (_Float16)v1.w);
            af[m] = __builtin_bit_cast(f16x8, h);
        }
        // prefetch next A chunk (no barrier -> latency hides under MFMA)
        if (ks < 7) {
            const int d = (ks + 1) * 32;
            aN[0][0] = *(const float4*)(a0 + d); aN[0][1] = *(const float4*)(a0 + d + 4);
            aN[1][0] = *(const float4*)(a1 + d); aN[1][1] = *(const float4*)(a1 + d + 4);
        }
#pragma unroll
        for (int m = 0; m < 2; ++m)
#pragma unroll
            for (int n = 0; n < 4; ++n)
                acc[m][n] = __builtin_amdgcn_mfma_f32_16x16x32_f16(af[m], bf[n], acc[m][n], 0, 0, 0);
    }

    // ---- epilogue: per-row top-2 over this block's 64 cols ----
    float cs[4];
#pragma unroll
    for (int n = 0; n < 4; ++n) cs[n] = csq[colbase + n * 16 + l15];

#pragma unroll
    for (int m = 0; m < 2; ++m) {
#pragma unroll
        for (int j = 0; j < 4; ++j) {
            float v1 = -3.4e38f, v2 = -3.4e38f;
            int i1 = 0, i2 = 0;
#pragma unroll
            for (int n = 0; n < 4; ++n) {
                const int col = colbase + n * 16 + l15;
                const float s = cs[n] - 2.0f * acc[m][n][j];
                if (s > v1) { v2 = v1; i2 = i1; v1 = s; i1 = col; }
                else if (s > v2) { v2 = s; i2 = col; }
            }
#pragma unroll
            for (int mk = 1; mk <= 8; mk <<= 1) {
                float ov1 = __shfl_xor(v1, mk, 64); int oi1 = __shfl_xor(i1, mk, 64);
                float ov2 = __shfl_xor(v2, mk, 64); int oi2 = __shfl_xor(i2, mk, 64);
                bool af_ = (v1 > ov1) || (v1 == ov1 && i1 < oi1);
                float f1 = af_ ? v1 : ov1; int g1 = af_ ? i1 : oi1;
                float c1 = af_ ? v2 : ov2; int d1 = af_ ? i2 : oi2;
                float c2 = af_ ? ov1 : v1; int d2 = af_ ? oi1 : i1;
                bool cf = (c1 > c2) || (c1 == c2 && d1 < d2);
                v1 = f1; i1 = g1; v2 = cf ? c1 : c2; i2 = cf ? d1 : d2;
            }
            if (l15 == 0) {
                const int row = wrow + m * 16 + l4 * 4 + j;
                float4 o = {v1, (float)i1, v2, (float)i2};
                *(float4*)(partials + ((((size_t)row << 3) + colblk) << 2)) = o;
            }
        }
    }
    if (colblk == 0) {
#pragma unroll
        for (int mk = 1; mk <= 32; mk <<= 1) e2 += __shfl_xor(e2, mk, 64);
        if (lane == 0) e2s[rowtile * 4 + wid] = e2;
    }
}

// ---------------- combine: merge 8 col-block top-2s, rescore near-ties ----------------
__global__ __launch_bounds__(256) void combine_kernel(
    const float* __restrict__ partials, const float* __restrict__ csq,
    const float* __restrict__ E, const float* __restrict__ Cg,
    float* __restrict__ out, float* __restrict__ sum2) {
    const int n = blockIdx.x * 256 + threadIdx.x;
    const float4* p = (const float4*)(partials + ((size_t)n << 5));
    float4 a = p[0];
    float v1 = a.x; int i1 = (int)a.y; float v2 = a.z; int i2 = (int)a.w;
#pragma unroll
    for (int cb = 1; cb < 8; ++cb) {
        float4 b = p[cb];
        float b1 = b.x; int j1 = (int)b.y; float b2 = b.z; int j2 = (int)b.w;
        bool af = (v1 > b1) || (v1 == b1 && i1 < j1);
        float f1 = af ? v1 : b1; int g1 = af ? i1 : j1;
        float c1 = af ? v2 : b2; int d1 = af ? i2 : j2;
        float c2 = af ? b1 : v1; int d2 = af ? j1 : i1;
        bool cf = (c1 > c2) || (c1 == c2 && d1 < d2);
        v1 = f1; i1 = g1; v2 = cf ? c1 : c2; i2 = cf ? d1 : d2;
    }
    if (v1 - v2 <= DELTA) {  // near-tie: exact fp32 rescore of both candidates
        const float* e = E + (size_t)n * ND;
        const float* c1p = Cg + (size_t)i1 * ND;
        const float* c2p = Cg + (size_t)i2 * ND;
        float d1 = 0.f, d2 = 0.f;
        for (int d = 0; d < ND; d += 4) {
            float4 ev = *(const float4*)(e + d);
            float4 cv1 = *(const float4*)(c1p + d);
            float4 cv2 = *(const float4*)(c2p + d);
            d1 += ev.x * cv1.x + ev.y * cv1.y + ev.z * cv1.z + ev.w * cv1.w;
            d2 += ev.x * cv2.x + ev.y * cv2.y + ev.z * cv2.z + ev.w * cv2.w;
        }
        float s1 = csq[i1] - 2.f * d1;
        float s2 = csq[i2] - 2.f * d2;
        if (s2 > s1 || (s2 == s1 && i2 < i1)) { v1 = s2; i1 = i2; } else { v1 = s1; }
    }
    out[1 + n] = (float)i1;
    float s = v1;
#pragma unroll
    for (int mk = 1; mk <= 32; mk <<= 1) s += __shfl_xor(s, mk, 64);
    __shared__ float w[4];
    const int lane = threadIdx.x & 63, wd = threadIdx.x >> 6;
    if (lane == 0) w[wd] = s;
    __syncthreads();
    if (threadIdx.x == 0) sum2[blockIdx.x] = w[0] + w[1] + w[2] + w[3];
}

// ---------------- final: loss = lambda^2 * (sum e^2 + sum row maxima) ----------------
__global__ __launch_bounds__(256) void final_kernel(const float* __restrict__ e2s,
                                                    const float* __restrict__ sum2,
                                                    float* __restrict__ out) {
    float s = 0.f;
    for (int i = threadIdx.x; i < 4096; i += 256) s += e2s[i];
    for (int i = threadIdx.x; i < 512; i += 256) s += sum2[i];
#pragma unroll
    for (int mk = 1; mk <= 32; mk <<= 1) s += __shfl_xor(s, mk, 64);
    __shared__ float w[4];
    const int lane = threadIdx.x & 63, wd = threadIdx.x >> 6;
    if (lane == 0) w[wd] = s;
    __syncthreads();
    if (threadIdx.x == 0) out[0] = LM2 * (w[0] + w[1] + w[2] + w[3]);
}

extern "C" void kernel_launch(void* const* d_in, const int* in_sizes, int n_in,
                              void* d_out, int out_size, void* d_ws, size_t ws_size,
                              hipStream_t stream) {
    (void)n_in; (void)out_size; (void)ws_size;
    const float* E = (const float*)d_in[0];
    const float* Cg = (const float*)d_in[1];
    float* out = (float*)d_out;

    // ws (floats): csq[512] | e2s[4096] | sum2[512] | Cf16 (256KB) | partials (16.8MB)
    float* wsf = (float*)d_ws;
    float* csq = wsf;
    float* e2s = wsf + 512;
    float* sum2 = wsf + 4608;
    unsigned short* Cf = (unsigned short*)(wsf + 5120);
    float* partials = wsf + 5120 + 65536;

    const int N = in_sizes[0] / ND;  // 131072
    const int nrowtiles = N >> 7;    // 1024

    prep_kernel<<<NK, 64, 0, stream>>>(Cg, csq, Cf);
    kmeans_mfma<<<nrowtiles * 8, 256, 0, stream>>>(E, Cf, csq, partials, e2s);
    combine_kernel<<<N / 256, 256, 0, stream>>>(partials, csq, E, Cg, out, sum2);
    final_kernel<<<1, 256, 0, stream>>>(e2s, sum2, out);
}

// Round 6
// 151.087 us; speedup vs baseline: 1.1243x; 1.1243x over previous
//
#include <hip/hip_runtime.h>

#define ND 256       // embedding dim
#define NK 512       // centroids
#define LM2 0.0625f  // lambda^2
#define DELTA 0.25f  // approx top-2 gap below this -> exact fp32 rescore

typedef _Float16 f16x8 __attribute__((ext_vector_type(8)));
typedef float f32x4 __attribute__((ext_vector_type(4)));
typedef unsigned short u16x8 __attribute__((ext_vector_type(8)));
typedef unsigned short u16x4 __attribute__((ext_vector_type(4)));

// ---------------- prep: csq[k] and fp16 centroids in MFMA-B-fragment order ----
// Cf layout: [colblk 4][(ks*4+l4) 32][col 128][8 halves]; granule = 16B = one
// lane's B-frag slice. Main kernel stages a colblk panel (64 KB) linearly and
// reads frags at the LDS streaming minimum (no conflicts, r4/r5-verified).
__global__ __launch_bounds__(64) void prep_kernel(const float* __restrict__ Cg,
                                                  float* __restrict__ csq,
                                                  unsigned short* __restrict__ Cf) {
    const int k = blockIdx.x, lane = threadIdx.x;
    float4 v = *(const float4*)(Cg + (size_t)k * ND + lane * 4);
    float s = v.x * v.x + v.y * v.y + v.z * v.z + v.w * v.w;
#pragma unroll
    for (int m = 1; m <= 32; m <<= 1) s += __shfl_xor(s, m, 64);
    if (lane == 0) csq[k] = s;
    u16x4 h;
    h[0] = __builtin_bit_cast(unsigned short, (_Float16)v.x);
    h[1] = __builtin_bit_cast(unsigned short, (_Float16)v.y);
    h[2] = __builtin_bit_cast(unsigned short, (_Float16)v.z);
    h[3] = __builtin_bit_cast(unsigned short, (_Float16)v.w);
    const int colblk = k >> 7, col = k & 127;
    const size_t idx = ((size_t)colblk << 15) + ((((size_t)(lane >> 1) << 7) + col) << 3) + ((lane & 1) << 2);
    *(u16x4*)(Cf + idx) = h;
}

// ---------------- main: A-in-registers, memory-free K-loop ----------------
// grid 4096 = 1024 rowtiles(128 rows) x 4 colblks(128 cols), XCD-chunked.
// block: 4 waves x 32-row tiles; wave tile 32x128. A loaded ONCE to regs
// (32 float4/thread), converted once to fp16 (A[2][8] = 64 VGPR); K-loop is
// pure {ds_read x8, MFMA x16} per ks -- no global ops, no per-ks vmcnt waits.
__global__ __launch_bounds__(256, 2) void kmeans_mfma(
    const float* __restrict__ E, const unsigned short* __restrict__ Cf,
    const float* __restrict__ csq, float* __restrict__ partials,
    float* __restrict__ e2s) {
    __shared__ unsigned short Blds[32768];  // 64 KB

    const int tid = threadIdx.x;
    const int l = ((blockIdx.x & 7) << 9) + (blockIdx.x >> 3);  // chunked XCD swizzle
    const int rowtile = l >> 2, colblk = l & 3;
    const int rowbase = rowtile << 7, colbase = colblk << 7;

    const int lane = tid & 63, wid = tid >> 6;
    const int l15 = lane & 15, l4 = lane >> 4;

    // ---- stage B panel (linear 64 KB copy) ----
    const unsigned short* CfB = Cf + ((size_t)colblk << 15);
#pragma unroll
    for (int i = 0; i < 16; ++i) {
        const int g = tid + i * 256;
        *(u16x8*)&Blds[g << 3] = *(const u16x8*)(CfB + ((size_t)g << 3));
    }

    // ---- load ALL of A once, convert to fp16 in registers ----
    const int wrow = rowbase + wid * 32;
    const float* a0 = E + (size_t)(wrow + l15) * ND + l4 * 8;       // m=0 row
    const float* a1 = E + (size_t)(wrow + 16 + l15) * ND + l4 * 8;  // m=1 row

    f16x8 A[2][8];  // [m][ks], 4 VGPR each
    float e2 = 0.f;
#pragma unroll
    for (int m = 0; m < 2; ++m) {
        const float* ap = m ? a1 : a0;
        float4 tmp[8][2];
#pragma unroll
        for (int ks = 0; ks < 8; ++ks) {  // issue all 16 loads back-to-back
            tmp[ks][0] = *(const float4*)(ap + ks * 32);
            tmp[ks][1] = *(const float4*)(ap + ks * 32 + 4);
        }
#pragma unroll
        for (int ks = 0; ks < 8; ++ks) {
            float4 v0 = tmp[ks][0], v1 = tmp[ks][1];
            if (colblk == 0)
                e2 += v0.x * v0.x + v0.y * v0.y + v0.z * v0.z + v0.w * v0.w +
                      v1.x * v1.x + v1.y * v1.y + v1.z * v1.z + v1.w * v1.w;
            u16x8 h;
            h[0] = __builtin_bit_cast(unsigned short, (_Float16)v0.x);
            h[1] = __builtin_bit_cast(unsigned short, (_Float16)v0.y);
            h[2] = __builtin_bit_cast(unsigned short, (_Float16)v0.z);
            h[3] = __builtin_bit_cast(unsigned short, (_Float16)v0.w);
            h[4] = __builtin_bit_cast(unsigned short, (_Float16)v1.x);
            h[5] = __builtin_bit_cast(unsigned short, (_Float16)v1.y);
            h[6] = __builtin_bit_cast(unsigned short, (_Float16)v1.z);
            h[7] = __builtin_bit_cast(unsigned short, (_Float16)v1.w);
            A[m][ks] = __builtin_bit_cast(f16x8, h);
        }
    }
    __syncthreads();  // B panel ready

    // ---- memory-free K-loop: 8 ks x {8 ds_read_b128, 16 MFMA} ----
    f32x4 acc[2][8] = {};
#pragma unroll
    for (int ks = 0; ks < 8; ++ks) {
        u16x8 bf[8];
#pragma unroll
        for (int n = 0; n < 8; ++n)
            bf[n] = *(const u16x8*)&Blds[((((ks << 2) + l4) << 7) + n * 16 + l15) << 3];
#pragma unroll
        for (int m = 0; m < 2; ++m)
#pragma unroll
            for (int n = 0; n < 8; ++n)
                acc[m][n] = __builtin_amdgcn_mfma_f32_16x16x32_f16(
                    A[m][ks], __builtin_bit_cast(f16x8, bf[n]), acc[m][n], 0, 0, 0);
    }

    // ---- epilogue: per-row top-2 over this block's 128 cols ----
    float cs[8];
#pragma unroll
    for (int n = 0; n < 8; ++n) cs[n] = csq[colbase + n * 16 + l15];

#pragma unroll
    for (int m = 0; m < 2; ++m) {
#pragma unroll
        for (int j = 0; j < 4; ++j) {
            float v1 = -3.4e38f, v2 = -3.4e38f;
            int i1 = 0, i2 = 0;
#pragma unroll
            for (int n = 0; n < 8; ++n) {
                const int col = colbase + n * 16 + l15;
                const float s = cs[n] - 2.0f * acc[m][n][j];
                if (s > v1) { v2 = v1; i2 = i1; v1 = s; i1 = col; }
                else if (s > v2) { v2 = s; i2 = col; }
            }
#pragma unroll
            for (int mk = 1; mk <= 8; mk <<= 1) {
                float ov1 = __shfl_xor(v1, mk, 64); int oi1 = __shfl_xor(i1, mk, 64);
                float ov2 = __shfl_xor(v2, mk, 64); int oi2 = __shfl_xor(i2, mk, 64);
                bool af_ = (v1 > ov1) || (v1 == ov1 && i1 < oi1);
                float f1 = af_ ? v1 : ov1; int g1 = af_ ? i1 : oi1;
                float c1 = af_ ? v2 : ov2; int d1 = af_ ? i2 : oi2;
                float c2 = af_ ? ov1 : v1; int d2 = af_ ? oi1 : i1;
                bool cf = (c1 > c2) || (c1 == c2 && d1 < d2);
                v1 = f1; i1 = g1; v2 = cf ? c1 : c2; i2 = cf ? d1 : d2;
            }
            if (l15 == 0) {
                const int row = wrow + m * 16 + l4 * 4 + j;
                float4 o = {v1, (float)i1, v2, (float)i2};
                *(float4*)(partials + ((((size_t)row << 2) + colblk) << 2)) = o;
            }
        }
    }
    if (colblk == 0) {
#pragma unroll
        for (int mk = 1; mk <= 32; mk <<= 1) e2 += __shfl_xor(e2, mk, 64);
        if (lane == 0) e2s[rowtile * 4 + wid] = e2;
    }
}

// ---------------- combine: merge 4 col-block top-2s, rescore near-ties ----------------
__global__ __launch_bounds__(256) void combine_kernel(
    const float* __restrict__ partials, const float* __restrict__ csq,
    const float* __restrict__ E, const float* __restrict__ Cg,
    float* __restrict__ out, float* __restrict__ sum2) {
    const int n = blockIdx.x * 256 + threadIdx.x;
    const float4* p = (const float4*)(partials + ((size_t)n << 4));
    float4 a = p[0];
    float v1 = a.x; int i1 = (int)a.y; float v2 = a.z; int i2 = (int)a.w;
#pragma unroll
    for (int cb = 1; cb < 4; ++cb) {
        float4 b = p[cb];
        float b1 = b.x; int j1 = (int)b.y; float b2 = b.z; int j2 = (int)b.w;
        bool af = (v1 > b1) || (v1 == b1 && i1 < j1);
        float f1 = af ? v1 : b1; int g1 = af ? i1 : j1;
        float c1 = af ? v2 : b2; int d1 = af ? i2 : j2;
        float c2 = af ? b1 : v1; int d2 = af ? j1 : i1;
        bool cf = (c1 > c2) || (c1 == c2 && d1 < d2);
        v1 = f1; i1 = g1; v2 = cf ? c1 : c2; i2 = cf ? d1 : d2;
    }
    if (v1 - v2 <= DELTA) {  // near-tie: exact fp32 rescore of both candidates
        const float* e = E + (size_t)n * ND;
        const float* c1p = Cg + (size_t)i1 * ND;
        const float* c2p = Cg + (size_t)i2 * ND;
        float d1 = 0.f, d2 = 0.f;
        for (int d = 0; d < ND; d += 4) {
            float4 ev = *(const float4*)(e + d);
            float4 cv1 = *(const float4*)(c1p + d);
            float4 cv2 = *(const float4*)(c2p + d);
            d1 += ev.x * cv1.x + ev.y * cv1.y + ev.z * cv1.z + ev.w * cv1.w;
            d2 += ev.x * cv2.x + ev.y * cv2.y + ev.z * cv2.z + ev.w * cv2.w;
        }
        float s1 = csq[i1] - 2.f * d1;
        float s2 = csq[i2] - 2.f * d2;
        if (s2 > s1 || (s2 == s1 && i2 < i1)) { v1 = s2; i1 = i2; } else { v1 = s1; }
    }
    out[1 + n] = (float)i1;
    float s = v1;
#pragma unroll
    for (int mk = 1; mk <= 32; mk <<= 1) s += __shfl_xor(s, mk, 64);
    __shared__ float w[4];
    const int lane = threadIdx.x & 63, wd = threadIdx.x >> 6;
    if (lane == 0) w[wd] = s;
    __syncthreads();
    if (threadIdx.x == 0) sum2[blockIdx.x] = w[0] + w[1] + w[2] + w[3];
}

// ---------------- final: loss = lambda^2 * (sum e^2 + sum row maxima) ----------------
__global__ __launch_bounds__(256) void final_kernel(const float* __restrict__ e2s,
                                                    const float* __restrict__ sum2,
                                                    float* __restrict__ out) {
    float s = 0.f;
    for (int i = threadIdx.x; i < 4096; i += 256) s += e2s[i];
    for (int i = threadIdx.x; i < 512; i += 256) s += sum2[i];
#pragma unroll
    for (int mk = 1; mk <= 32; mk <<= 1) s += __shfl_xor(s, mk, 64);
    __shared__ float w[4];
    const int lane = threadIdx.x & 63, wd = threadIdx.x >> 6;
    if (lane == 0) w[wd] = s;
    __syncthreads();
    if (threadIdx.x == 0) out[0] = LM2 * (w[0] + w[1] + w[2] + w[3]);
}

extern "C" void kernel_launch(void* const* d_in, const int* in_sizes, int n_in,
                              void* d_out, int out_size, void* d_ws, size_t ws_size,
                              hipStream_t stream) {
    (void)n_in; (void)out_size; (void)ws_size;
    const float* E = (const float*)d_in[0];
    const float* Cg = (const float*)d_in[1];
    float* out = (float*)d_out;

    // ws (floats): csq[512] | e2s[4096] | sum2[512] | Cf16 (256KB) | partials (8MB)
    float* wsf = (float*)d_ws;
    float* csq = wsf;
    float* e2s = wsf + 512;
    float* sum2 = wsf + 4608;
    unsigned short* Cf = (unsigned short*)(wsf + 5120);
    float* partials = wsf + 5120 + 65536;

    const int N = in_sizes[0] / ND;  // 131072
    const int nrowtiles = N >> 7;    // 1024

    prep_kernel<<<NK, 64, 0, stream>>>(Cg, csq, Cf);
    kmeans_mfma<<<nrowtiles * 4, 256, 0, stream>>>(E, Cf, csq, partials, e2s);
    combine_kernel<<<N / 256, 256, 0, stream>>>(partials, csq, E, Cg, out, sum2);
    final_kernel<<<1, 256, 0, stream>>>(e2s, sum2, out);
}